// Round 6
// baseline (123.189 us; speedup 1.0000x reference)
//
#include <hip/hip_runtime.h>
#include <math.h>

// Problem constants: V=50257, H=2048, E=1024, L=4
#define LSTM_H 2048
#define LSTM_E 1024
#define LSTM_L 4
#define FOURH  8192

__device__ __forceinline__ float sigmoidf_(float x) {
    return 1.0f / (1.0f + __expf(-x));
}

__device__ __forceinline__ float wave_reduce(float s) {
    #pragma unroll
    for (int off = 32; off > 0; off >>= 1)
        s += __shfl_down(s, off, 64);
    return s;
}

// ---------------- K1: ALL dependency-free dots, pure row-mode ----------------
// Blocks [0,2048):    W_ih0 rows. Wave w handles row r=4b+w (4KB contiguous);
//                     writes A[r] = dot + b_ih[0][r] + b_hh[0][r].
// Blocks [2048,10240): W_hh rows, all 4 layers (R=0..32767, 8KB rows).
//                     layer0 -> B[r] (raw); layers1-3 -> part[l-1][r] (+biases).
__global__ __launch_bounds__(256)
void k1_rows(const int*   __restrict__ token,
             const float* __restrict__ hidden,  // [L,1,H]
             const float* __restrict__ emb,     // [V,E]
             const float* __restrict__ W_ih0,   // [4H,E]
             const float* __restrict__ W_hh,    // [L,4H,H]
             const float* __restrict__ b_ih,    // [L,4H]
             const float* __restrict__ b_hh,    // [L,4H]
             float* __restrict__ A,             // [4H]
             float* __restrict__ B,             // [4H]
             float* __restrict__ part)          // [3][4H]
{
    const int wave = threadIdx.x >> 6;
    const int lane = threadIdx.x & 63;

    if (blockIdx.x < 2048) {
        const int r = blockIdx.x * 4 + wave;           // 0..8191
        const float4* w4 = (const float4*)(W_ih0 + (size_t)r * LSTM_E);
        const float4* v4 = (const float4*)(emb + (size_t)(*token) * LSTM_E);
        float s = 0.f;
        #pragma unroll
        for (int t = 0; t < 4; ++t) {
            const int idx = lane + t * 64;
            float4 a = w4[idx], b = v4[idx];
            s += a.x * b.x + a.y * b.y + a.z * b.z + a.w * b.w;
        }
        s = wave_reduce(s);
        if (lane == 0) A[r] = s + b_ih[r] + b_hh[r];
    } else {
        const int R     = (blockIdx.x - 2048) * 4 + wave;   // 0..32767
        const int layer = R >> 13;
        const int rowin = R & (FOURH - 1);
        const float4* w4 = (const float4*)(W_hh + (size_t)layer * FOURH * LSTM_H
                                                 + (size_t)rowin * LSTM_H);
        const float4* v4 = (const float4*)(hidden + (size_t)layer * LSTM_H);
        float s = 0.f;
        #pragma unroll
        for (int t = 0; t < 8; ++t) {
            const int idx = lane + t * 64;
            float4 a = w4[idx], b = v4[idx];
            s += a.x * b.x + a.y * b.y + a.z * b.z + a.w * b.w;
        }
        s = wave_reduce(s);
        if (lane == 0) {
            if (layer == 0) B[rowin] = s;
            else {
                const size_t br = (size_t)layer * FOURH + rowin;
                part[(size_t)(layer - 1) * FOURH + rowin] = s + b_ih[br] + b_hh[br];
            }
        }
    }
}

// ---------------- KB: activate prev layer (redundant) + row-mode dots --------
// grid 2048 blocks. Wave w: row r=4b+w of W (8KB, prefetched to regs).
// Prologue: every block computes FULL h_prev (+c_prev) from gate buffers into
// LDS; blocks 0..255 also write h_new/c_new for prev layer (units 8b..8b+7).
// Then gates_out[r] = dot(W[r], h_lds) + partl[r].
__global__ __launch_bounds__(256)
void kb_rows(const float* __restrict__ W,        // [4H,H] weight slice (W_ihR[l-1])
             const float* __restrict__ partl,    // [4H] hh-part (+biases) for layer l
             const float* __restrict__ gA,       // [4H] gate term 1 (prev layer)
             const float* __restrict__ gB,       // [4H] gate term 2 or nullptr
             const float* __restrict__ c_in,     // [H] cell input of prev layer
             float* __restrict__ h_out_g,        // [H] h_new slot of prev layer
             float* __restrict__ c_out_g,        // [H] c_new slot of prev layer
             float* __restrict__ gates_out)      // [4H] gates of layer l
{
    __shared__ __align__(16) float h_lds[LSTM_H];
    __shared__ __align__(16) float c_lds[LSTM_H];

    const int t    = threadIdx.x;
    const int wave = t >> 6;
    const int lane = t & 63;
    const int r    = blockIdx.x * 4 + wave;

    // Prefetch the full 8KB weight row into registers: HBM stream starts now,
    // latency hides under the activation prologue.
    const float4* __restrict__ w4 = (const float4*)(W + (size_t)r * LSTM_H);
    float4 wreg[8];
    #pragma unroll
    for (int i = 0; i < 8; ++i) wreg[i] = w4[lane + i * 64];

    const float p = partl[r];   // independent scalar, prefetch too

    // Prologue: activation of previous layer (all 2048 units per block).
    #pragma unroll
    for (int u = 0; u < 8; ++u) {
        const int j = t + 256 * u;
        float gi, gf, gg, go;
        if (gB) {
            gi = gA[j]          + gB[j];
            gf = gA[j + 2048]   + gB[j + 2048];
            gg = gA[j + 4096]   + gB[j + 4096];
            go = gA[j + 6144]   + gB[j + 6144];
        } else {
            gi = gA[j]; gf = gA[j + 2048]; gg = gA[j + 4096]; go = gA[j + 6144];
        }
        const float i_ = sigmoidf_(gi);
        const float f_ = sigmoidf_(gf);
        const float g_ = tanhf(gg);
        const float o_ = sigmoidf_(go);
        const float c  = f_ * c_in[j] + i_ * g_;
        c_lds[j] = c;
        h_lds[j] = o_ * tanhf(c);
    }
    __syncthreads();

    if (blockIdx.x < 256 && t < 8) {
        const int j = blockIdx.x * 8 + t;
        h_out_g[j] = h_lds[j];
        c_out_g[j] = c_lds[j];
    }

    // Row dot against LDS-resident h.
    const float4* __restrict__ h4 = (const float4*)h_lds;
    float s = 0.f;
    #pragma unroll
    for (int i = 0; i < 8; ++i) {
        float4 v = h4[lane + i * 64];
        s += wreg[i].x * v.x + wreg[i].y * v.y + wreg[i].z * v.z + wreg[i].w * v.w;
    }
    s = wave_reduce(s);
    if (lane == 0) gates_out[r] = s + p;
}

// ---------------- FC: activate layer 3 (redundant) + row-mode dots -----------
// grid 256 blocks. Block b: rows 4b..4b+3 of fc_W; writes h_new/c_new for
// layer 3 units 8b..8b+7.
__global__ __launch_bounds__(256)
void kfc_rows(const float* __restrict__ fc_W,    // [E,H]
              const float* __restrict__ fc_b,    // [E]
              const float* __restrict__ g3,      // [4H] gates of layer 3
              const float* __restrict__ c_in,    // [H] cell[3]
              float* __restrict__ h_out_g,       // [H] h_new layer 3
              float* __restrict__ c_out_g,       // [H] c_new layer 3
              float* __restrict__ decoded)       // [E]
{
    __shared__ __align__(16) float h_lds[LSTM_H];
    __shared__ __align__(16) float c_lds[LSTM_H];

    const int t    = threadIdx.x;
    const int wave = t >> 6;
    const int lane = t & 63;
    const int r    = blockIdx.x * 4 + wave;

    const float4* __restrict__ w4 = (const float4*)(fc_W + (size_t)r * LSTM_H);
    float4 wreg[8];
    #pragma unroll
    for (int i = 0; i < 8; ++i) wreg[i] = w4[lane + i * 64];

    const float fb = fc_b[r];

    #pragma unroll
    for (int u = 0; u < 8; ++u) {
        const int j = t + 256 * u;
        const float i_ = sigmoidf_(g3[j]);
        const float f_ = sigmoidf_(g3[j + 2048]);
        const float g_ = tanhf(g3[j + 4096]);
        const float o_ = sigmoidf_(g3[j + 6144]);
        const float c  = f_ * c_in[j] + i_ * g_;
        c_lds[j] = c;
        h_lds[j] = o_ * tanhf(c);
    }
    __syncthreads();

    if (t < 8) {
        const int j = blockIdx.x * 8 + t;
        h_out_g[j] = h_lds[j];
        c_out_g[j] = c_lds[j];
    }

    const float4* __restrict__ h4 = (const float4*)h_lds;
    float s = 0.f;
    #pragma unroll
    for (int i = 0; i < 8; ++i) {
        float4 v = h4[lane + i * 64];
        s += wreg[i].x * v.x + wreg[i].y * v.y + wreg[i].z * v.z + wreg[i].w * v.w;
    }
    s = wave_reduce(s);
    if (lane == 0) decoded[r] = s + fb;
}

extern "C" void kernel_launch(void* const* d_in, const int* in_sizes, int n_in,
                              void* d_out, int out_size, void* d_ws, size_t ws_size,
                              hipStream_t stream) {
    const int*   token  = (const int*)d_in[0];
    const float* hidden = (const float*)d_in[1];
    const float* cell   = (const float*)d_in[2];
    const float* emb    = (const float*)d_in[3];
    const float* W_ih0  = (const float*)d_in[4];
    const float* W_ihR  = (const float*)d_in[5];
    const float* W_hh   = (const float*)d_in[6];
    const float* b_ih   = (const float*)d_in[7];
    const float* b_hh   = (const float*)d_in[8];
    const float* fc_W   = (const float*)d_in[9];
    const float* fc_b   = (const float*)d_in[10];

    float* out     = (float*)d_out;
    float* decoded = out;                               // [E]
    float* h_new   = out + LSTM_E;                      // [L*H]
    float* c_new   = out + LSTM_E + LSTM_L * LSTM_H;    // [L*H]

    // ws layout (floats)
    float* ws    = (float*)d_ws;
    float* A     = ws;                   // [4H]  ih-dot layer0 + biases
    float* B     = ws + FOURH;           // [4H]  hh-dot layer0 (raw)
    float* part  = ws + 2 * FOURH;       // [3][4H] hh-dot layers1-3 + biases
    float* gates = ws + 5 * FOURH;       // [3][4H] gates of layers 1,2,3

    const size_t WIH_STRIDE = (size_t)FOURH * LSTM_H;

    // K1: all dependency-free dots (297.5 MB), pure row-mode.
    k1_rows<<<10240, 256, 0, stream>>>(
        token, hidden, emb, W_ih0, W_hh, b_ih, b_hh, A, B, part);

    // KB1: activate layer 0 + dots for layer 1.
    kb_rows<<<2048, 256, 0, stream>>>(
        W_ihR, part, A, B,
        cell, h_new, c_new, gates);

    // KB2: activate layer 1 + dots for layer 2.
    kb_rows<<<2048, 256, 0, stream>>>(
        W_ihR + WIH_STRIDE, part + FOURH, gates, nullptr,
        cell + LSTM_H, h_new + LSTM_H, c_new + LSTM_H, gates + FOURH);

    // KB3: activate layer 2 + dots for layer 3.
    kb_rows<<<2048, 256, 0, stream>>>(
        W_ihR + 2 * WIH_STRIDE, part + 2 * FOURH, gates + FOURH, nullptr,
        cell + 2 * LSTM_H, h_new + 2 * LSTM_H, c_new + 2 * LSTM_H, gates + 2 * FOURH);

    // FC: activate layer 3 + decode.
    kfc_rows<<<LSTM_E / 4, 256, 0, stream>>>(
        fc_W, fc_b, gates + 2 * FOURH,
        cell + 3 * LSTM_H, h_new + 3 * LSTM_H, c_new + 3 * LSTM_H, decoded);
}

// Round 7
// 105.393 us; speedup vs baseline: 1.1689x; 1.1689x over previous
//
#include <hip/hip_runtime.h>
#include <math.h>

// Problem constants: V=50257, H=2048, E=1024, L=4
#define LSTM_H 2048
#define LSTM_E 1024
#define LSTM_L 4
#define FOURH  8192

__device__ __forceinline__ float sigmoidf_(float x) {
    return 1.0f / (1.0f + __expf(-x));
}

__device__ __forceinline__ float wave_reduce(float s) {
    #pragma unroll
    for (int off = 32; off > 0; off >>= 1)
        s += __shfl_down(s, off, 64);
    return s;
}

__device__ __forceinline__ float dot2048(const float* __restrict__ w,
                                         const float* __restrict__ v, int lane) {
    const float4* __restrict__ w4 = (const float4*)w;
    const float4* __restrict__ v4 = (const float4*)v;
    float s = 0.0f;
    #pragma unroll
    for (int t = 0; t < 8; ++t) {
        const int idx = lane + t * 64;
        float4 a = w4[idx];
        float4 b = v4[idx];
        s += a.x * b.x + a.y * b.y + a.z * b.z + a.w * b.w;
    }
    return s;
}

__device__ __forceinline__ float dot1024(const float* __restrict__ w,
                                         const float* __restrict__ v, int lane) {
    const float4* __restrict__ w4 = (const float4*)w;
    const float4* __restrict__ v4 = (const float4*)v;
    float s = 0.0f;
    #pragma unroll
    for (int t = 0; t < 4; ++t) {
        const int idx = lane + t * 64;
        float4 a = w4[idx];
        float4 b = v4[idx];
        s += a.x * b.x + a.y * b.y + a.z * b.z + a.w * b.w;
    }
    return s;
}

// ---------------- K1: all dependency-free work ----------------
// Blocks [0, 2048): unit-mode layer 0 (r5-proven shape) — full gates + cell
//   update for unit j. 2 streams/wave (W_ih0 row + W_hh0 row).
// Blocks [2048, 3584): row-mode W_hh partials for layers 1..3, 4 CONSECUTIVE
//   rows per wave read sequentially (32KB/wave stream; block = 16 rows =
//   128KB contiguous). h vector staged in LDS once per block.
__global__ __launch_bounds__(256)
void k1_parallel(const int*   __restrict__ token,
                 const float* __restrict__ hidden,  // [L,1,H]
                 const float* __restrict__ cell,    // [L,1,H]
                 const float* __restrict__ emb,     // [V,E]
                 const float* __restrict__ W_ih0,   // [4H,E]
                 const float* __restrict__ W_hh,    // [L,4H,H]
                 const float* __restrict__ b_ih,    // [L,4H]
                 const float* __restrict__ b_hh,    // [L,4H]
                 float* __restrict__ h_new,         // [L*H]
                 float* __restrict__ c_new,         // [L*H]
                 float* __restrict__ part)          // [3][4H]
{
    __shared__ __align__(16) float4 vlds[LSTM_H / 4];  // 8KB (row-mode)
    __shared__ float gsh[4];                           // (unit-mode)

    const int wave = threadIdx.x >> 6;
    const int lane = threadIdx.x & 63;

    if (blockIdx.x < 2048) {
        // ---- unit-mode: layer 0, unit j (identical to round 5) ----
        const int j   = blockIdx.x;
        const int row = wave * LSTM_H + j;

        const float bias  = b_ih[row] + b_hh[row];
        const float c_in0 = cell[j];
        const float* xemb = emb + (size_t)(*token) * LSTM_E;

        float s = dot1024(W_ih0 + (size_t)row * LSTM_E, xemb, lane)
                + dot2048(W_hh  + (size_t)row * LSTM_H, hidden, lane);
        s = wave_reduce(s);

        if (lane == 0) gsh[wave] = s + bias;
        __syncthreads();

        if (threadIdx.x == 0) {
            const float i_ = sigmoidf_(gsh[0]);
            const float f_ = sigmoidf_(gsh[1]);
            const float g_ = tanhf(gsh[2]);
            const float o_ = sigmoidf_(gsh[3]);
            const float c  = f_ * c_in0 + i_ * g_;
            c_new[j] = c;
            h_new[j] = o_ * tanhf(c);
        }
    } else {
        // ---- row-mode: layers 1..3 W_hh, 4 sequential rows per wave ----
        const int blk       = blockIdx.x - 2048;        // 0..1535
        const int base_blk  = blk * 16;                 // first row of block (0..24560)
        const int layer_off = base_blk >> 13;           // 0..2 (same for whole block)
        const int layer     = layer_off + 1;            // actual W_hh layer 1..3
        const int rbase     = (base_blk & (FOURH - 1)) + wave * 4;  // row within layer

        // Stage h[layer] into LDS once per block.
        const float4* __restrict__ vg =
            (const float4*)(hidden + (size_t)layer * LSTM_H);
        for (int k = threadIdx.x; k < LSTM_H / 4; k += 256)
            vlds[k] = vg[k];
        __syncthreads();

        const float4* __restrict__ w4 =
            (const float4*)(W_hh + ((size_t)layer * FOURH + rbase) * LSTM_H);

        float acc[4];
        #pragma unroll
        for (int r = 0; r < 4; ++r) {
            const float4* __restrict__ wr = w4 + (size_t)r * (LSTM_H / 4);
            float s = 0.f;
            #pragma unroll
            for (int t = 0; t < 8; ++t) {
                const int idx = lane + t * 64;
                float4 a = wr[idx];
                float4 b = vlds[idx];
                s += a.x * b.x + a.y * b.y + a.z * b.z + a.w * b.w;
            }
            acc[r] = s;
        }

        #pragma unroll
        for (int r = 0; r < 4; ++r) {
            const float s = wave_reduce(acc[r]);
            if (lane == 0) {
                const size_t br = (size_t)layer * FOURH + rbase + r;
                part[(size_t)layer_off * FOURH + rbase + r] =
                    s + b_ih[br] + b_hh[br];
            }
        }
    }
}

// ---------------- KB: sequential part of layer l (round-5 proven) ----------
__global__ __launch_bounds__(256)
void kb_layer(const float* __restrict__ W_ih,   // [4H, H] (layer's W_ihR slice)
              const float* __restrict__ part_l, // [4H] W_hh part + biases
              const float* __restrict__ hx,     // [H] h_{l-1}
              const float* __restrict__ c_in,   // [H]
              float* __restrict__ h_out,        // [H]
              float* __restrict__ c_out)        // [H]
{
    const int j    = blockIdx.x;
    const int wave = threadIdx.x >> 6;
    const int lane = threadIdx.x & 63;
    const int row  = wave * LSTM_H + j;

    const float p      = part_l[row];
    const float c_in_j = c_in[j];

    float s = dot2048(W_ih + (size_t)row * LSTM_H, hx, lane);
    s = wave_reduce(s);

    __shared__ float gsh[4];
    if (lane == 0) gsh[wave] = s + p;
    __syncthreads();

    if (threadIdx.x == 0) {
        const float i_ = sigmoidf_(gsh[0]);
        const float f_ = sigmoidf_(gsh[1]);
        const float g_ = tanhf(gsh[2]);
        const float o_ = sigmoidf_(gsh[3]);
        const float c  = f_ * c_in_j + i_ * g_;
        c_out[j] = c;
        h_out[j] = o_ * tanhf(c);
    }
}

// ---------------- FC: decoded = fc_W @ h3 + fc_b (round-5 proven) -----------
__global__ __launch_bounds__(256)
void kfc(const float* __restrict__ fc_W,   // [E, H]
         const float* __restrict__ fc_b,   // [E]
         const float* __restrict__ h,      // [H]
         float* __restrict__ out)          // [E]
{
    const int wave = threadIdx.x >> 6;
    const int lane = threadIdx.x & 63;
    const int r = blockIdx.x * 4 + wave;

    const float b = fc_b[r];
    float s = dot2048(fc_W + (size_t)r * LSTM_H, h, lane);
    s = wave_reduce(s);
    if (lane == 0) out[r] = s + b;
}

extern "C" void kernel_launch(void* const* d_in, const int* in_sizes, int n_in,
                              void* d_out, int out_size, void* d_ws, size_t ws_size,
                              hipStream_t stream) {
    const int*   token  = (const int*)d_in[0];
    const float* hidden = (const float*)d_in[1];
    const float* cell   = (const float*)d_in[2];
    const float* emb    = (const float*)d_in[3];
    const float* W_ih0  = (const float*)d_in[4];
    const float* W_ihR  = (const float*)d_in[5];
    const float* W_hh   = (const float*)d_in[6];
    const float* b_ih   = (const float*)d_in[7];
    const float* b_hh   = (const float*)d_in[8];
    const float* fc_W   = (const float*)d_in[9];
    const float* fc_b   = (const float*)d_in[10];

    float* out     = (float*)d_out;
    float* decoded = out;                              // [E]
    float* h_new   = out + LSTM_E;                     // [L*H]
    float* c_new   = out + LSTM_E + LSTM_L * LSTM_H;   // [L*H]
    float* part    = (float*)d_ws;                     // [3][4H] = 96 KB

    const size_t WIH_STRIDE = (size_t)FOURH * LSTM_H;
    const size_t P_STRIDE   = (size_t)FOURH;

    // K1: layer-0 full (unit-mode) + W_hh partials (4-row sequential streams).
    k1_parallel<<<3584, 256, 0, stream>>>(
        token, hidden, cell, emb, W_ih0, W_hh, b_ih, b_hh,
        h_new, c_new, part);

    // Sequential chain: layers 1..3 (67 MB each).
    for (int l = 1; l < LSTM_L; ++l) {
        kb_layer<<<LSTM_H, 256, 0, stream>>>(
            W_ihR + (size_t)(l - 1) * WIH_STRIDE,
            part  + (size_t)(l - 1) * P_STRIDE,
            h_new + (size_t)(l - 1) * LSTM_H,
            cell  + (size_t)l * LSTM_H,
            h_new + (size_t)l * LSTM_H,
            c_new + (size_t)l * LSTM_H);
    }

    // FC (8.4 MB).
    kfc<<<LSTM_E / 4, 256, 0, stream>>>(
        fc_W, fc_b, h_new + (size_t)(LSTM_L - 1) * LSTM_H, decoded);
}

// Round 8
// 86.624 us; speedup vs baseline: 1.4221x; 1.2167x over previous
//
#include <hip/hip_runtime.h>
#include <math.h>

// Problem constants: V=50257, H=2048, E=1024, L=4
#define LSTM_H 2048
#define LSTM_E 1024
#define LSTM_L 4
#define FOURH  8192

// Native clang vector type so __builtin_nontemporal_load accepts it.
typedef float f32x4 __attribute__((ext_vector_type(4)));

__device__ __forceinline__ float sigmoidf_(float x) {
    return 1.0f / (1.0f + __expf(-x));
}

__device__ __forceinline__ float wave_reduce(float s) {
    #pragma unroll
    for (int off = 32; off > 0; off >>= 1)
        s += __shfl_down(s, off, 64);
    return s;
}

// Regular cached dot (weights expected to be L3-resident across replays).
__device__ __forceinline__ float dot2048(const float* __restrict__ w,
                                         const float* __restrict__ v, int lane) {
    const float4* __restrict__ w4 = (const float4*)w;
    const float4* __restrict__ v4 = (const float4*)v;
    float s = 0.0f;
    #pragma unroll
    for (int t = 0; t < 8; ++t) {
        const int idx = lane + t * 64;
        float4 a = w4[idx];
        float4 b = v4[idx];
        s += a.x * b.x + a.y * b.y + a.z * b.z + a.w * b.w;
    }
    return s;
}

__device__ __forceinline__ float dot1024(const float* __restrict__ w,
                                         const float* __restrict__ v, int lane) {
    const float4* __restrict__ w4 = (const float4*)w;
    const float4* __restrict__ v4 = (const float4*)v;
    float s = 0.0f;
    #pragma unroll
    for (int t = 0; t < 4; ++t) {
        const int idx = lane + t * 64;
        float4 a = w4[idx];
        float4 b = v4[idx];
        s += a.x * b.x + a.y * b.y + a.z * b.z + a.w * b.w;
    }
    return s;
}

// Non-temporal weight stream (W_hh: single-use per replay; keep OUT of L3 so
// the 232MB of W_ih0/W_ihR/fc_W can stay LLC-resident across graph replays).
__device__ __forceinline__ float dot2048_wnt(const float* __restrict__ w,
                                             const float* __restrict__ v, int lane) {
    const f32x4*  __restrict__ w4 = (const f32x4*)w;
    const float4* __restrict__ v4 = (const float4*)v;
    float s = 0.0f;
    #pragma unroll
    for (int t = 0; t < 8; ++t) {
        const int idx = lane + t * 64;
        f32x4  a = __builtin_nontemporal_load(w4 + idx);
        float4 b = v4[idx];
        s += a.x * b.x + a.y * b.y + a.z * b.z + a.w * b.w;
    }
    return s;
}

// ---------------- K1: all dependency-free work (round-5 structure) ----------
// Blocks [0, 2048): unit-mode layer 0 — full gates + cell update for unit j.
//   W_ih0 row cached (L3-pinned set), W_hh0 row non-temporal.
// Blocks [2048, 8192): row-mode W_hh partials for layers 1..3 (1 row/wave,
//   block = 4 consecutive rows = 32KB). W_hh rows non-temporal.
__global__ __launch_bounds__(256)
void k1_parallel(const int*   __restrict__ token,
                 const float* __restrict__ hidden,  // [L,1,H]
                 const float* __restrict__ cell,    // [L,1,H]
                 const float* __restrict__ emb,     // [V,E]
                 const float* __restrict__ W_ih0,   // [4H,E]
                 const float* __restrict__ W_hh,    // [L,4H,H]
                 const float* __restrict__ b_ih,    // [L,4H]
                 const float* __restrict__ b_hh,    // [L,4H]
                 float* __restrict__ h_new,         // [L*H]
                 float* __restrict__ c_new,         // [L*H]
                 float* __restrict__ part)          // [3][4H]
{
    const int wave = threadIdx.x >> 6;
    const int lane = threadIdx.x & 63;

    if (blockIdx.x < 2048) {
        // ---- unit-mode: layer 0, unit j ----
        const int j   = blockIdx.x;
        const int row = wave * LSTM_H + j;

        const float bias  = b_ih[row] + b_hh[row];
        const float c_in0 = cell[j];
        const float* xemb = emb + (size_t)(*token) * LSTM_E;

        float s = dot1024(W_ih0 + (size_t)row * LSTM_E, xemb, lane)
                + dot2048_wnt(W_hh + (size_t)row * LSTM_H, hidden, lane);
        s = wave_reduce(s);

        __shared__ float gsh[4];
        if (lane == 0) gsh[wave] = s + bias;
        __syncthreads();

        if (threadIdx.x == 0) {
            const float i_ = sigmoidf_(gsh[0]);
            const float f_ = sigmoidf_(gsh[1]);
            const float g_ = tanhf(gsh[2]);
            const float o_ = sigmoidf_(gsh[3]);
            const float c  = f_ * c_in0 + i_ * g_;
            c_new[j] = c;
            h_new[j] = o_ * tanhf(c);
        }
    } else {
        // ---- row-mode: W_hh partial for layers 1..3 (1 row per wave) ----
        const int r     = (blockIdx.x - 2048) * 4 + wave;   // 0..24575
        const int lidx  = r >> 13;          // 0..2  -> layer lidx+1
        const int rowin = r & (FOURH - 1);  // row within the layer's [4H]

        const size_t brow = (size_t)(lidx + 1) * FOURH + rowin;
        const float bias = b_ih[brow] + b_hh[brow];

        const float* w = W_hh + (size_t)(lidx + 1) * FOURH * LSTM_H
                               + (size_t)rowin * LSTM_H;
        const float* v = hidden + (size_t)(lidx + 1) * LSTM_H;

        float s = dot2048_wnt(w, v, lane);
        s = wave_reduce(s);
        if (lane == 0) part[r] = s + bias;
    }
}

// ---------------- KB: sequential part of layer l (round-5 proven) ----------
// W_ihR reads stay CACHED — this is the stream we want L3-resident.
__global__ __launch_bounds__(256)
void kb_layer(const float* __restrict__ W_ih,   // [4H, H] (layer's W_ihR slice)
              const float* __restrict__ part_l, // [4H] W_hh part + biases
              const float* __restrict__ hx,     // [H] h_{l-1}
              const float* __restrict__ c_in,   // [H]
              float* __restrict__ h_out,        // [H]
              float* __restrict__ c_out)        // [H]
{
    const int j    = blockIdx.x;
    const int wave = threadIdx.x >> 6;
    const int lane = threadIdx.x & 63;
    const int row  = wave * LSTM_H + j;

    const float p      = part_l[row];
    const float c_in_j = c_in[j];

    float s = dot2048(W_ih + (size_t)row * LSTM_H, hx, lane);
    s = wave_reduce(s);

    __shared__ float gsh[4];
    if (lane == 0) gsh[wave] = s + p;
    __syncthreads();

    if (threadIdx.x == 0) {
        const float i_ = sigmoidf_(gsh[0]);
        const float f_ = sigmoidf_(gsh[1]);
        const float g_ = tanhf(gsh[2]);
        const float o_ = sigmoidf_(gsh[3]);
        const float c  = f_ * c_in_j + i_ * g_;
        c_out[j] = c;
        h_out[j] = o_ * tanhf(c);
    }
}

// ---------------- FC: decoded = fc_W @ h3 + fc_b (round-5 proven) -----------
__global__ __launch_bounds__(256)
void kfc(const float* __restrict__ fc_W,   // [E, H]
         const float* __restrict__ fc_b,   // [E]
         const float* __restrict__ h,      // [H]
         float* __restrict__ out)          // [E]
{
    const int wave = threadIdx.x >> 6;
    const int lane = threadIdx.x & 63;
    const int r = blockIdx.x * 4 + wave;

    const float b = fc_b[r];
    float s = dot2048(fc_W + (size_t)r * LSTM_H, h, lane);
    s = wave_reduce(s);
    if (lane == 0) out[r] = s + b;
}

extern "C" void kernel_launch(void* const* d_in, const int* in_sizes, int n_in,
                              void* d_out, int out_size, void* d_ws, size_t ws_size,
                              hipStream_t stream) {
    const int*   token  = (const int*)d_in[0];
    const float* hidden = (const float*)d_in[1];
    const float* cell   = (const float*)d_in[2];
    const float* emb    = (const float*)d_in[3];
    const float* W_ih0  = (const float*)d_in[4];
    const float* W_ihR  = (const float*)d_in[5];
    const float* W_hh   = (const float*)d_in[6];
    const float* b_ih   = (const float*)d_in[7];
    const float* b_hh   = (const float*)d_in[8];
    const float* fc_W   = (const float*)d_in[9];
    const float* fc_b   = (const float*)d_in[10];

    float* out     = (float*)d_out;
    float* decoded = out;                              // [E]
    float* h_new   = out + LSTM_E;                     // [L*H]
    float* c_new   = out + LSTM_E + LSTM_L * LSTM_H;   // [L*H]
    float* part    = (float*)d_ws;                     // [3][4H] = 96 KB

    const size_t WIH_STRIDE = (size_t)FOURH * LSTM_H;
    const size_t P_STRIDE   = (size_t)FOURH;

    // K1: layer-0 full + all W_hh partials (297.5 MB), W_hh non-temporal.
    k1_parallel<<<8192, 256, 0, stream>>>(
        token, hidden, cell, emb, W_ih0, W_hh, b_ih, b_hh,
        h_new, c_new, part);

    // Sequential chain: layers 1..3 (67 MB each, cached reads -> L3 target).
    for (int l = 1; l < LSTM_L; ++l) {
        kb_layer<<<LSTM_H, 256, 0, stream>>>(
            W_ihR + (size_t)(l - 1) * WIH_STRIDE,
            part  + (size_t)(l - 1) * P_STRIDE,
            h_new + (size_t)(l - 1) * LSTM_H,
            cell  + (size_t)l * LSTM_H,
            h_new + (size_t)l * LSTM_H,
            c_new + (size_t)l * LSTM_H);
    }

    // FC (8.4 MB, cached).
    kfc<<<LSTM_E / 4, 256, 0, stream>>>(
        fc_W, fc_b, h_new + (size_t)(LSTM_L - 1) * LSTM_H, decoded);
}

// Round 9
// 85.916 us; speedup vs baseline: 1.4338x; 1.0082x over previous
//
#include <hip/hip_runtime.h>
#include <math.h>

// Problem constants: V=50257, H=2048, E=1024, L=4
#define LSTM_H 2048
#define LSTM_E 1024
#define LSTM_L 4
#define FOURH  8192

// Native clang vector type so __builtin_nontemporal_load accepts it.
typedef float f32x4 __attribute__((ext_vector_type(4)));

__device__ __forceinline__ float sigmoidf_(float x) {
    return 1.0f / (1.0f + __expf(-x));
}

__device__ __forceinline__ float wave_reduce(float s) {
    #pragma unroll
    for (int off = 32; off > 0; off >>= 1)
        s += __shfl_down(s, off, 64);
    return s;
}

// Regular cached dot (weights expected to be L3-resident across replays).
__device__ __forceinline__ float dot2048(const float* __restrict__ w,
                                         const float* __restrict__ v, int lane) {
    const float4* __restrict__ w4 = (const float4*)w;
    const float4* __restrict__ v4 = (const float4*)v;
    float s = 0.0f;
    #pragma unroll
    for (int t = 0; t < 8; ++t) {
        const int idx = lane + t * 64;
        float4 a = w4[idx];
        float4 b = v4[idx];
        s += a.x * b.x + a.y * b.y + a.z * b.z + a.w * b.w;
    }
    return s;
}

__device__ __forceinline__ float dot1024(const float* __restrict__ w,
                                         const float* __restrict__ v, int lane) {
    const float4* __restrict__ w4 = (const float4*)w;
    const float4* __restrict__ v4 = (const float4*)v;
    float s = 0.0f;
    #pragma unroll
    for (int t = 0; t < 4; ++t) {
        const int idx = lane + t * 64;
        float4 a = w4[idx];
        float4 b = v4[idx];
        s += a.x * b.x + a.y * b.y + a.z * b.z + a.w * b.w;
    }
    return s;
}

// Non-temporal weight stream (bulk of W_hh: single-use per replay; keep OUT of
// L3 so W_ih0/W_ihR/fc_W + a 16MB slice of W_hh stay LLC-resident).
__device__ __forceinline__ float dot2048_wnt(const float* __restrict__ w,
                                             const float* __restrict__ v, int lane) {
    const f32x4*  __restrict__ w4 = (const f32x4*)w;
    const float4* __restrict__ v4 = (const float4*)v;
    float s = 0.0f;
    #pragma unroll
    for (int t = 0; t < 8; ++t) {
        const int idx = lane + t * 64;
        f32x4  a = __builtin_nontemporal_load(w4 + idx);
        float4 b = v4[idx];
        s += a.x * b.x + a.y * b.y + a.z * b.z + a.w * b.w;
    }
    return s;
}

// ---------------- K1: all dependency-free work (round-8 structure) ----------
// Blocks [0, 2048): unit-mode layer 0 — full gates + cell update for unit j.
//   W_ih0 row cached (L3-pinned set), W_hh0 row non-temporal.
// Blocks [2048, 8192): row-mode W_hh partials for layers 1..3 (1 row/wave,
//   block = 4 consecutive rows = 32KB). W_hh rows non-temporal EXCEPT the
//   last 2048 rows (16MB) which stay cached -> L3-resident across replays.
__global__ __launch_bounds__(256)
void k1_parallel(const int*   __restrict__ token,
                 const float* __restrict__ hidden,  // [L,1,H]
                 const float* __restrict__ cell,    // [L,1,H]
                 const float* __restrict__ emb,     // [V,E]
                 const float* __restrict__ W_ih0,   // [4H,E]
                 const float* __restrict__ W_hh,    // [L,4H,H]
                 const float* __restrict__ b_ih,    // [L,4H]
                 const float* __restrict__ b_hh,    // [L,4H]
                 float* __restrict__ h_new,         // [L*H]
                 float* __restrict__ c_new,         // [L*H]
                 float* __restrict__ part)          // [3][4H]
{
    const int wave = threadIdx.x >> 6;
    const int lane = threadIdx.x & 63;

    if (blockIdx.x < 2048) {
        // ---- unit-mode: layer 0, unit j ----
        const int j   = blockIdx.x;
        const int row = wave * LSTM_H + j;

        const float bias  = b_ih[row] + b_hh[row];
        const float c_in0 = cell[j];
        const float* xemb = emb + (size_t)(*token) * LSTM_E;

        float s = dot1024(W_ih0 + (size_t)row * LSTM_E, xemb, lane)
                + dot2048_wnt(W_hh + (size_t)row * LSTM_H, hidden, lane);
        s = wave_reduce(s);

        __shared__ float gsh[4];
        if (lane == 0) gsh[wave] = s + bias;
        __syncthreads();

        if (threadIdx.x == 0) {
            const float i_ = sigmoidf_(gsh[0]);
            const float f_ = sigmoidf_(gsh[1]);
            const float g_ = tanhf(gsh[2]);
            const float o_ = sigmoidf_(gsh[3]);
            const float c  = f_ * c_in0 + i_ * g_;
            c_new[j] = c;
            h_new[j] = o_ * tanhf(c);
        }
    } else {
        // ---- row-mode: W_hh partial for layers 1..3 (1 row per wave) ----
        const int r     = (blockIdx.x - 2048) * 4 + wave;   // 0..24575
        const int lidx  = r >> 13;          // 0..2  -> layer lidx+1
        const int rowin = r & (FOURH - 1);  // row within the layer's [4H]

        const size_t brow = (size_t)(lidx + 1) * FOURH + rowin;
        const float bias = b_ih[brow] + b_hh[brow];

        const float* w = W_hh + (size_t)(lidx + 1) * FOURH * LSTM_H
                               + (size_t)rowin * LSTM_H;
        const float* v = hidden + (size_t)(lidx + 1) * LSTM_H;

        // Last 2048 rows (16MB) of the 24576-row range stay CACHED: they join
        // the L3-resident set and skip HBM on subsequent replays.
        const bool cached = (r >= 24576 - 2048);
        float s = cached ? dot2048(w, v, lane) : dot2048_wnt(w, v, lane);
        s = wave_reduce(s);
        if (lane == 0) part[r] = s + bias;
    }
}

// ---------------- KB: sequential part of layer l (round-5 proven) ----------
// W_ihR reads stay CACHED — this is the stream we want L3-resident.
__global__ __launch_bounds__(256)
void kb_layer(const float* __restrict__ W_ih,   // [4H, H] (layer's W_ihR slice)
              const float* __restrict__ part_l, // [4H] W_hh part + biases
              const float* __restrict__ hx,     // [H] h_{l-1}
              const float* __restrict__ c_in,   // [H]
              float* __restrict__ h_out,        // [H]
              float* __restrict__ c_out)        // [H]
{
    const int j    = blockIdx.x;
    const int wave = threadIdx.x >> 6;
    const int lane = threadIdx.x & 63;
    const int row  = wave * LSTM_H + j;

    const float p      = part_l[row];
    const float c_in_j = c_in[j];

    float s = dot2048(W_ih + (size_t)row * LSTM_H, hx, lane);
    s = wave_reduce(s);

    __shared__ float gsh[4];
    if (lane == 0) gsh[wave] = s + p;
    __syncthreads();

    if (threadIdx.x == 0) {
        const float i_ = sigmoidf_(gsh[0]);
        const float f_ = sigmoidf_(gsh[1]);
        const float g_ = tanhf(gsh[2]);
        const float o_ = sigmoidf_(gsh[3]);
        const float c  = f_ * c_in_j + i_ * g_;
        c_out[j] = c;
        h_out[j] = o_ * tanhf(c);
    }
}

// ---------------- FC: decoded = fc_W @ h3 + fc_b (round-5 proven) -----------
__global__ __launch_bounds__(256)
void kfc(const float* __restrict__ fc_W,   // [E, H]
         const float* __restrict__ fc_b,   // [E]
         const float* __restrict__ h,      // [H]
         float* __restrict__ out)          // [E]
{
    const int wave = threadIdx.x >> 6;
    const int lane = threadIdx.x & 63;
    const int r = blockIdx.x * 4 + wave;

    const float b = fc_b[r];
    float s = dot2048(fc_W + (size_t)r * LSTM_H, h, lane);
    s = wave_reduce(s);
    if (lane == 0) out[r] = s + b;
}

extern "C" void kernel_launch(void* const* d_in, const int* in_sizes, int n_in,
                              void* d_out, int out_size, void* d_ws, size_t ws_size,
                              hipStream_t stream) {
    const int*   token  = (const int*)d_in[0];
    const float* hidden = (const float*)d_in[1];
    const float* cell   = (const float*)d_in[2];
    const float* emb    = (const float*)d_in[3];
    const float* W_ih0  = (const float*)d_in[4];
    const float* W_ihR  = (const float*)d_in[5];
    const float* W_hh   = (const float*)d_in[6];
    const float* b_ih   = (const float*)d_in[7];
    const float* b_hh   = (const float*)d_in[8];
    const float* fc_W   = (const float*)d_in[9];
    const float* fc_b   = (const float*)d_in[10];

    float* out     = (float*)d_out;
    float* decoded = out;                              // [E]
    float* h_new   = out + LSTM_E;                     // [L*H]
    float* c_new   = out + LSTM_E + LSTM_L * LSTM_H;   // [L*H]
    float* part    = (float*)d_ws;                     // [3][4H] = 96 KB

    const size_t WIH_STRIDE = (size_t)FOURH * LSTM_H;
    const size_t P_STRIDE   = (size_t)FOURH;

    // K1: layer-0 full + all W_hh partials; W_hh nt except 16MB cached slice.
    k1_parallel<<<8192, 256, 0, stream>>>(
        token, hidden, cell, emb, W_ih0, W_hh, b_ih, b_hh,
        h_new, c_new, part);

    // Sequential chain: layers 1..3 (67 MB each, cached reads -> L3 target).
    for (int l = 1; l < LSTM_L; ++l) {
        kb_layer<<<LSTM_H, 256, 0, stream>>>(
            W_ihR + (size_t)(l - 1) * WIH_STRIDE,
            part  + (size_t)(l - 1) * P_STRIDE,
            h_new + (size_t)(l - 1) * LSTM_H,
            cell  + (size_t)l * LSTM_H,
            h_new + (size_t)l * LSTM_H,
            c_new + (size_t)l * LSTM_H);
    }

    // FC (8.4 MB, cached).
    kfc<<<LSTM_E / 4, 256, 0, stream>>>(
        fc_W, fc_b, h_new + (size_t)(LSTM_L - 1) * LSTM_H, decoded);
}